// Round 1
// 1931.950 us; speedup vs baseline: 1.0330x; 1.0330x over previous
//
#include <hip/hip_runtime.h>
#include <hip/hip_bf16.h>

#define T_ 512
#define B_ 256
#define I_ 256
#define H_ 512

#define NG 16   // batch row-groups of 16 rows
#define NS 4    // column slices of 128 cols

// exchange ring: [2 slots][NG][H_ cols][8 row-pairs] u64, self-tagged words
#define RING_WPG (H_ * 8)                            // words per (slot,group)
#define RING_BYTES (2ull * NG * RING_WPG * 8)        // 1 MiB

typedef _Float16 f16x8 __attribute__((ext_vector_type(8)));
typedef float f32x4 __attribute__((ext_vector_type(4)));

__device__ __forceinline__ float tanh_fast(float v) {
  float e = __expf(2.0f * v);
  return 1.0f - 2.0f / (e + 1.0f);
}

__device__ __forceinline__ f16x8 cvt8(const float4 a, const float4 b) {
  f16x8 f;
  f[0] = (_Float16)a.x; f[1] = (_Float16)a.y; f[2] = (_Float16)a.z; f[3] = (_Float16)a.w;
  f[4] = (_Float16)b.x; f[5] = (_Float16)b.y; f[6] = (_Float16)b.z; f[7] = (_Float16)b.w;
  return f;
}

__device__ __forceinline__ unsigned long long pack2h(_Float16 a, _Float16 b, unsigned tag) {
  unsigned ua = __builtin_bit_cast(unsigned short, a);
  unsigned ub = __builtin_bit_cast(unsigned short, b);
  return (unsigned long long)(ua | (ub << 16)) | ((unsigned long long)tag << 32);
}

// -------------------------------------------------------------------------
// Persistent fused recurrence: 64 blocks x 256 threads, 1 block/CU.
// group g = bid & 15 (rows g*16..+16); slice s = bid >> 4 (cols s*128..+128)
//
// Latency-overlap restructure (this round): per step, everything that does
// NOT depend on remote h_t runs while the ring poll loads are in flight:
//   (1) issue 12 poll loads      (fire-and-forget)
//   (2) issue x_t global loads
//   (3) hs[t-1] writeback        (reads hbuf own, global store)
//   (4) M1: own-column h MFMAs   (8/wave, hbuf own slice is local)
//   (5) x cvt -> xbuf; poll-check loop; stage remote h -> hbuf
//   B2  __syncthreads
//   (7) M2: remote-K h MFMAs (24/wave) + x MFMAs (16/wave)
//   (8) tanh; RING STORES FIRST (fabric ASAP); hbuf own writes
//   B1  __syncthreads
// W_hh fragments stored ROTATED (whh[0..3] = own K-tiles, whh[4..15] =
// remote, wrapping) so M1/M2 index the register array with compile-time
// indices only (runtime-indexed reg arrays -> scratch).
// -------------------------------------------------------------------------
__global__ __launch_bounds__(256, 1) void rnn_recurrence(
    const float* __restrict__ x,      // [T,B,I]
    const float* __restrict__ w_ih,   // [H,I]
    const float* __restrict__ w_hh,   // [H,H]
    const float* __restrict__ b_ih,   // [H]
    const float* __restrict__ b_hh,   // [H]
    unsigned long long* __restrict__ ring,
    _Float16* __restrict__ hs)        // [T,B,H]; hs[t] = h_{t+1}
{
  const int tid  = threadIdx.x;
  const int lane = tid & 63;
  const int w    = tid >> 6;        // wave 0..3
  const int bid  = blockIdx.x;
  const int g    = bid & 15;        // row group
  const int s    = bid >> 4;        // col slice
  const int r0   = g * 16;
  const int c0   = s * 128;
  const int lrow = lane & 15;
  const int quad = lane >> 4;
  const int kq   = quad * 8;

  __shared__ _Float16 hbuf[16][512 + 8];
  __shared__ _Float16 xbuf[16][256 + 8];

  // ---- weight fragments into registers (per wave: n-tiles 2w, 2w+1)
  // whh stored rotated: logical tile kt corresponds to physical K-tile
  // pk = (s*4 + kt) & 15, so kt 0..3 is always the OWN K-range.
  f16x8 whh0[16], whh1[16];
  f16x8 wih0[8], wih1[8];
  const int n0c = c0 + (2 * w + 0) * 16 + lrow;   // global col of acc0
  const int n1c = c0 + (2 * w + 1) * 16 + lrow;   // global col of acc1
  const float bias0 = b_ih[n0c] + b_hh[n0c];
  const float bias1 = b_ih[n1c] + b_hh[n1c];
  #pragma unroll
  for (int kt = 0; kt < 16; ++kt) {
    const int pk = (s * 4 + kt) & 15;
    const int k  = pk * 32 + kq;
    whh0[kt] = cvt8(*(const float4*)(w_hh + (size_t)n0c * H_ + k),
                    *(const float4*)(w_hh + (size_t)n0c * H_ + k + 4));
    whh1[kt] = cvt8(*(const float4*)(w_hh + (size_t)n1c * H_ + k),
                    *(const float4*)(w_hh + (size_t)n1c * H_ + k + 4));
  }
  #pragma unroll
  for (int kt = 0; kt < 8; ++kt) {
    const int k = kt * 32 + kq;
    wih0[kt] = cvt8(*(const float4*)(w_ih + (size_t)n0c * I_ + k),
                    *(const float4*)(w_ih + (size_t)n0c * I_ + k + 4));
    wih1[kt] = cvt8(*(const float4*)(w_ih + (size_t)n1c * I_ + k),
                    *(const float4*)(w_ih + (size_t)n1c * I_ + k + 4));
  }

  // ---- per-thread remote-word map: 3 remote slices x 128 cols x 8 pairs
  // keep only roff in registers; colf = roff>>3, prow = (roff&7)*2 derived.
  int roff[12];
  #pragma unroll
  for (int j = 0; j < 12; ++j) {
    const int wdx = tid + j * 256;            // 0..3071
    const int rs  = wdx >> 10;                // remote slice idx 0..2
    const int sl  = rs + (rs >= s ? 1 : 0);   // actual slice (skip own)
    const int c   = (wdx >> 3) & 127;
    const int p   = wdx & 7;
    roff[j] = (sl * 128 + c) * 8 + p;
  }

  // ---- init own LDS slice to h_0 = 0
  {
    const int row = tid >> 4, ch = tid & 15;          // 256 = 16 rows x 16 chunks
    f16x8 z = {0, 0, 0, 0, 0, 0, 0, 0};
    *(f16x8*)(&hbuf[row][c0 + ch * 8]) = z;
  }
  __syncthreads();   // own slice ready for first M1

  const int xrow = tid >> 5;
  const int xcol = (tid & 31) * 8;

  for (int t = 0; t < T_; ++t) {
    // ---- (1) issue poll loads for remote h_t (check deferred past M1)
    const unsigned long long* rg =
        ring + ((size_t)((t & 1) ? NG : 0) + g) * RING_WPG;
    unsigned long long v[12];
    #pragma unroll
    for (int j = 0; j < 12; ++j)
      v[j] = __hip_atomic_load(&rg[roff[j]], __ATOMIC_RELAXED,
                               __HIP_MEMORY_SCOPE_AGENT);

    // ---- (2) issue x_t loads (consumed after M1)
    const float* src = x + ((size_t)t * B_ + r0) * I_;
    const float4 xv0 = *(const float4*)(src + (size_t)xrow * I_ + xcol);
    const float4 xv1 = *(const float4*)(src + (size_t)xrow * I_ + xcol + 4);
    const float4 xv2 = *(const float4*)(src + (size_t)(xrow + 8) * I_ + xcol);
    const float4 xv3 = *(const float4*)(src + (size_t)(xrow + 8) * I_ + xcol + 4);

    // ---- (3) hs[t-1] = h_t own slice (fire-and-forget global store)
    if (t > 0) {
      const int row = tid >> 4, ch = tid & 15;
      *(uint4*)(hs + ((size_t)(t - 1) * B_ + r0 + row) * H_ + c0 + ch * 8) =
          *(const uint4*)(&hbuf[row][c0 + ch * 8]);
    }

    // ---- (4) M1: own-column K-range of h_t @ W_hh (local, no remote dep)
    f32x4 a0a = {0.f,0.f,0.f,0.f}, a0b = {0.f,0.f,0.f,0.f};
    f32x4 a1a = {0.f,0.f,0.f,0.f}, a1b = {0.f,0.f,0.f,0.f};
    #pragma unroll
    for (int kt = 0; kt < 4; ++kt) {
      const int pk = (s * 4 + kt) & 15;
      const f16x8 a = *(const f16x8*)(&hbuf[lrow][pk * 32 + kq]);
      a0b = __builtin_amdgcn_mfma_f32_16x16x32_f16(a, whh0[kt], a0b, 0, 0, 0);
      a1b = __builtin_amdgcn_mfma_f32_16x16x32_f16(a, whh1[kt], a1b, 0, 0, 0);
    }

    // ---- (5a) x_t -> xbuf
    *(f16x8*)(&xbuf[xrow][xcol])     = cvt8(xv0, xv1);
    *(f16x8*)(&xbuf[xrow + 8][xcol]) = cvt8(xv2, xv3);

    // ---- (5b) poll-check remote h_t, then stage into hbuf
    {
      bool again = true;
      while (again) {
        again = false;
        #pragma unroll
        for (int j = 0; j < 12; ++j) {
          if ((unsigned)(v[j] >> 32) != (unsigned)t) {
            v[j] = __hip_atomic_load(&rg[roff[j]], __ATOMIC_RELAXED,
                                     __HIP_MEMORY_SCOPE_AGENT);
            again = true;
          }
        }
      }
      #pragma unroll
      for (int j = 0; j < 12; ++j) {
        const int col = roff[j] >> 3;
        const int pr  = (roff[j] & 7) * 2;
        const unsigned lo = (unsigned)v[j];
        hbuf[pr + 0][col] =
            __builtin_bit_cast(_Float16, (unsigned short)(lo & 0xffff));
        hbuf[pr + 1][col] =
            __builtin_bit_cast(_Float16, (unsigned short)(lo >> 16));
      }
    }
    __syncthreads();   // B2: remote h_t + x_t staged; M1/C reads of hbuf done

    // ---- (7) M2: remote K-range of h_t @ W_hh + x_t @ W_ih
    #pragma unroll
    for (int kt = 4; kt < 16; ++kt) {
      const int pk = (s * 4 + kt) & 15;
      const f16x8 a = *(const f16x8*)(&hbuf[lrow][pk * 32 + kq]);
      if (kt < 10) {
        a0a = __builtin_amdgcn_mfma_f32_16x16x32_f16(a, whh0[kt], a0a, 0, 0, 0);
        a1a = __builtin_amdgcn_mfma_f32_16x16x32_f16(a, whh1[kt], a1a, 0, 0, 0);
      } else {
        a0b = __builtin_amdgcn_mfma_f32_16x16x32_f16(a, whh0[kt], a0b, 0, 0, 0);
        a1b = __builtin_amdgcn_mfma_f32_16x16x32_f16(a, whh1[kt], a1b, 0, 0, 0);
      }
    }
    #pragma unroll
    for (int kt = 0; kt < 8; ++kt) {
      const f16x8 a = *(const f16x8*)(&xbuf[lrow][kt * 32 + kq]);
      if (kt < 4) {
        a0a = __builtin_amdgcn_mfma_f32_16x16x32_f16(a, wih0[kt], a0a, 0, 0, 0);
        a1a = __builtin_amdgcn_mfma_f32_16x16x32_f16(a, wih1[kt], a1a, 0, 0, 0);
      } else {
        a0b = __builtin_amdgcn_mfma_f32_16x16x32_f16(a, wih0[kt], a0b, 0, 0, 0);
        a1b = __builtin_amdgcn_mfma_f32_16x16x32_f16(a, wih1[kt], a1b, 0, 0, 0);
      }
    }
    const f32x4 acc0 = a0a + a0b;
    const f32x4 acc1 = a1a + a1b;

    // ---- (8) tanh; ring stores FIRST (publish ASAP), then own LDS writes
    _Float16 e0[4], e1[4];
    #pragma unroll
    for (int r = 0; r < 4; ++r) {
      e0[r] = (_Float16)tanh_fast(acc0[r] + bias0);
      e1[r] = (_Float16)tanh_fast(acc1[r] + bias1);
    }
    {
      unsigned long long* rn =
          ring + ((size_t)(((t + 1) & 1) ? NG : 0) + g) * RING_WPG;
      const unsigned tag = (unsigned)(t + 1);
      __hip_atomic_store(&rn[n0c * 8 + quad * 2 + 0], pack2h(e0[0], e0[1], tag),
                         __ATOMIC_RELAXED, __HIP_MEMORY_SCOPE_AGENT);
      __hip_atomic_store(&rn[n0c * 8 + quad * 2 + 1], pack2h(e0[2], e0[3], tag),
                         __ATOMIC_RELAXED, __HIP_MEMORY_SCOPE_AGENT);
      __hip_atomic_store(&rn[n1c * 8 + quad * 2 + 0], pack2h(e1[0], e1[1], tag),
                         __ATOMIC_RELAXED, __HIP_MEMORY_SCOPE_AGENT);
      __hip_atomic_store(&rn[n1c * 8 + quad * 2 + 1], pack2h(e1[2], e1[3], tag),
                         __ATOMIC_RELAXED, __HIP_MEMORY_SCOPE_AGENT);
    }
    #pragma unroll
    for (int r = 0; r < 4; ++r) {
      hbuf[quad * 4 + r][n0c] = e0[r];
      hbuf[quad * 4 + r][n1c] = e1[r];
    }
    __syncthreads();   // B1: h_{t+1} own slice visible for next M1 / hs write
  }

  // ---- final: hs[T-1] = h_T own slice
  {
    const int row = tid >> 4, ch = tid & 15;
    *(uint4*)(hs + ((size_t)(T_ - 1) * B_ + r0 + row) * H_ + c0 + ch * 8) =
        *(const uint4*)(&hbuf[row][c0 + ch * 8]);
  }
}

// -------------------------------------------------------------------------
// Output head: out[m,o] = hs[m,:] @ w_fc[o,:] + b_fc[o]
// M=T*B=131072, N=256, K=512. 64x64 block tile, 4 waves in 2x2.
// Grid: n-dimension FASTEST (blockIdx.x = n-block) so the 4 blocks sharing
// an A-tile dispatch consecutively -> hs tile served from L2/LLC (was 4x HBM).
// -------------------------------------------------------------------------
__global__ __launch_bounds__(256) void fc_head(
    const _Float16* __restrict__ hs,  // [T*B, H]
    const float* __restrict__ w_fc,   // [I, H]
    const float* __restrict__ b_fc,   // [I]
    float* __restrict__ out)          // [T*B, I]
{
  const int tid  = threadIdx.x;
  const int lane = tid & 63;
  const int w    = tid >> 6;
  const int wm   = w & 1;
  const int wn   = w >> 1;
  const int m0   = blockIdx.y * 64;
  const int n0   = blockIdx.x * 64;
  const int lrow = lane & 15;
  const int quad = lane >> 4;
  const int kq   = quad * 8;

  __shared__ _Float16 As[64][32 + 8];
  __shared__ _Float16 Bs[64][32 + 8];

  f32x4 acc00 = {0.f,0.f,0.f,0.f}, acc01 = {0.f,0.f,0.f,0.f};
  f32x4 acc10 = {0.f,0.f,0.f,0.f}, acc11 = {0.f,0.f,0.f,0.f};

  const int srow = tid >> 2;
  const int skc  = (tid & 3) * 8;

  for (int k0 = 0; k0 < H_; k0 += 32) {
    *(uint4*)(&As[srow][skc]) =
        *(const uint4*)(hs + (size_t)(m0 + srow) * H_ + k0 + skc);
    *(f16x8*)(&Bs[srow][skc]) =
        cvt8(*(const float4*)(w_fc + (size_t)(n0 + srow) * H_ + k0 + skc),
             *(const float4*)(w_fc + (size_t)(n0 + srow) * H_ + k0 + skc + 4));
    __syncthreads();

    const f16x8 a0 = *(const f16x8*)(&As[wm * 32 + lrow][kq]);
    const f16x8 a1 = *(const f16x8*)(&As[wm * 32 + 16 + lrow][kq]);
    const f16x8 b0 = *(const f16x8*)(&Bs[wn * 32 + lrow][kq]);
    const f16x8 b1 = *(const f16x8*)(&Bs[wn * 32 + 16 + lrow][kq]);
    acc00 = __builtin_amdgcn_mfma_f32_16x16x32_f16(a0, b0, acc00, 0, 0, 0);
    acc01 = __builtin_amdgcn_mfma_f32_16x16x32_f16(a0, b1, acc01, 0, 0, 0);
    acc10 = __builtin_amdgcn_mfma_f32_16x16x32_f16(a1, b0, acc10, 0, 0, 0);
    acc11 = __builtin_amdgcn_mfma_f32_16x16x32_f16(a1, b1, acc11, 0, 0, 0);
    __syncthreads();
  }

  #pragma unroll
  for (int ni = 0; ni < 2; ++ni) {
    const int col = n0 + wn * 32 + ni * 16 + lrow;
    const float bf = b_fc[col];
    #pragma unroll
    for (int mi = 0; mi < 2; ++mi) {
      const f32x4 a = (mi == 0) ? (ni == 0 ? acc00 : acc01)
                                : (ni == 0 ? acc10 : acc11);
      #pragma unroll
      for (int r = 0; r < 4; ++r) {
        const int rowm = m0 + wm * 32 + mi * 16 + quad * 4 + r;
        out[(size_t)rowm * I_ + col] = a[r] + bf;
      }
    }
  }
}

extern "C" void kernel_launch(void* const* d_in, const int* in_sizes, int n_in,
                              void* d_out, int out_size, void* d_ws, size_t ws_size,
                              hipStream_t stream) {
  const float* x    = (const float*)d_in[0];
  const float* w_ih = (const float*)d_in[1];
  const float* w_hh = (const float*)d_in[2];
  const float* b_ih = (const float*)d_in[3];
  const float* b_hh = (const float*)d_in[4];
  const float* w_fc = (const float*)d_in[5];
  const float* b_fc = (const float*)d_in[6];
  float* out = (float*)d_out;

  unsigned long long* ring = (unsigned long long*)d_ws;
  _Float16* hs = (_Float16*)((char*)d_ws + RING_BYTES);

  // zero ring slot 0 -> (tag 0, h0 = 0) words; slot 1 poison tag never matches
  hipMemsetAsync(d_ws, 0, (size_t)NG * RING_WPG * 8, stream);

  rnn_recurrence<<<64, 256, 0, stream>>>(x, w_ih, w_hh, b_ih, b_hh, ring, hs);
  fc_head<<<dim3(4, 2048), 256, 0, stream>>>(hs, w_fc, b_fc, out);
}

// Round 2
// 1705.552 us; speedup vs baseline: 1.1702x; 1.1327x over previous
//
#include <hip/hip_runtime.h>
#include <hip/hip_bf16.h>

#define T_ 512
#define B_ 256
#define I_ 256
#define H_ 512

#define NG 16   // batch row-groups of 16 rows
#define NS 4    // column slices of 128 cols

// exchange rings: [2 slots][NG][H_ cols][8 row-pairs] u64, self-tagged words
// ring  (atomic, device-coherent)  at d_ws + 0
// ringf (fast, XCD-L2 local)       at d_ws + RING_BYTES
#define RING_WPG (H_ * 8)                            // words per (slot,group)
#define RING_BYTES (2ull * NG * RING_WPG * 8)        // 1 MiB each

typedef _Float16 f16x8 __attribute__((ext_vector_type(8)));
typedef float f32x4 __attribute__((ext_vector_type(4)));

__device__ __forceinline__ float tanh_fast(float v) {
  float e = __expf(2.0f * v);
  return 1.0f - 2.0f / (e + 1.0f);
}

__device__ __forceinline__ f16x8 cvt8(const float4 a, const float4 b) {
  f16x8 f;
  f[0] = (_Float16)a.x; f[1] = (_Float16)a.y; f[2] = (_Float16)a.z; f[3] = (_Float16)a.w;
  f[4] = (_Float16)b.x; f[5] = (_Float16)b.y; f[6] = (_Float16)b.z; f[7] = (_Float16)b.w;
  return f;
}

__device__ __forceinline__ unsigned long long pack2h(_Float16 a, _Float16 b, unsigned tag) {
  unsigned ua = __builtin_bit_cast(unsigned short, a);
  unsigned ub = __builtin_bit_cast(unsigned short, b);
  return (unsigned long long)(ua | (ub << 16)) | ((unsigned long long)tag << 32);
}

// -------------------------------------------------------------------------
// Persistent fused recurrence: 64 blocks x 256 threads, 1 block/CU.
// group g = bid & 15 (rows g*16..+16); slice s = bid >> 4 (cols s*128..+128)
// -> the 4 blocks of a group are bids {g, g+16, g+32, g+48}: same XCD under
//    round-robin dispatch (bid mod 8 equal).
//
// h exchange, this round: DUAL-PUBLISH + PROBE + COMMIT.
//  fast path: plain global_store -> same-XCD L2; consumer spins with
//             inline-asm `global_load_dwordx2 ... sc0` (bypass L1, served
//             by local L2, ~300cy round) on self-tagged words.
//  probe:     at t==1 (first real exchange) each thread tries <=256 fast
//             rounds; failures fall back to the agent-atomic ring and vote
//             "slow" in LDS. Vote is group-consistent: a non-uniform XCD
//             assignment gives EVERY member >=1 cross-XCD partner.
//  commit:    t>=2 fast mode = L2-only publish+poll (no atomics, no fabric);
//             slow mode = atomic-only (exactly the verified old path).
// Correctness never depends on the XCD mapping, only speed does.
// -------------------------------------------------------------------------
__global__ __launch_bounds__(256, 1) void rnn_recurrence(
    const float* __restrict__ x,      // [T,B,I]
    const float* __restrict__ w_ih,   // [H,I]
    const float* __restrict__ w_hh,   // [H,H]
    const float* __restrict__ b_ih,   // [H]
    const float* __restrict__ b_hh,   // [H]
    unsigned long long* __restrict__ ring,    // atomic (coherent)
    unsigned long long* __restrict__ ringf,   // fast (XCD-L2)
    _Float16* __restrict__ hs)        // [T,B,H]; hs[t] = h_{t+1}
{
  const int tid  = threadIdx.x;
  const int lane = tid & 63;
  const int w    = tid >> 6;        // wave 0..3
  const int bid  = blockIdx.x;
  const int g    = bid & 15;        // row group
  const int s    = bid >> 4;        // col slice
  const int r0   = g * 16;
  const int c0   = s * 128;
  const int lrow = lane & 15;
  const int quad = lane >> 4;
  const int kq   = quad * 8;

  __shared__ _Float16 hbuf[16][512 + 8];
  __shared__ _Float16 xbuf[16][256 + 8];
  __shared__ int g_ok;

  // ---- weight fragments into registers (per wave: n-tiles 2w, 2w+1)
  // whh stored ROTATED: logical tile kt -> physical K-tile pk=(s*4+kt)&15,
  // so kt 0..3 is always the OWN K-range (compile-time indices only).
  f16x8 whh0[16], whh1[16];
  f16x8 wih0[8], wih1[8];
  const int n0c = c0 + (2 * w + 0) * 16 + lrow;   // global col of acc0
  const int n1c = c0 + (2 * w + 1) * 16 + lrow;   // global col of acc1
  const float bias0 = b_ih[n0c] + b_hh[n0c];
  const float bias1 = b_ih[n1c] + b_hh[n1c];
  #pragma unroll
  for (int kt = 0; kt < 16; ++kt) {
    const int pk = (s * 4 + kt) & 15;
    const int k  = pk * 32 + kq;
    whh0[kt] = cvt8(*(const float4*)(w_hh + (size_t)n0c * H_ + k),
                    *(const float4*)(w_hh + (size_t)n0c * H_ + k + 4));
    whh1[kt] = cvt8(*(const float4*)(w_hh + (size_t)n1c * H_ + k),
                    *(const float4*)(w_hh + (size_t)n1c * H_ + k + 4));
  }
  #pragma unroll
  for (int kt = 0; kt < 8; ++kt) {
    const int k = kt * 32 + kq;
    wih0[kt] = cvt8(*(const float4*)(w_ih + (size_t)n0c * I_ + k),
                    *(const float4*)(w_ih + (size_t)n0c * I_ + k + 4));
    wih1[kt] = cvt8(*(const float4*)(w_ih + (size_t)n1c * I_ + k),
                    *(const float4*)(w_ih + (size_t)n1c * I_ + k + 4));
  }

  // ---- per-thread remote-word map: 3 remote slices x 128 cols x 8 pairs
  int roff[12];   // u64-word offset within a (slot,group)
  int obyte[12];  // byte offset for the asm saddr-form loads
  #pragma unroll
  for (int j = 0; j < 12; ++j) {
    const int wdx = tid + j * 256;            // 0..3071
    const int rs  = wdx >> 10;                // remote slice idx 0..2
    const int sl  = rs + (rs >= s ? 1 : 0);   // actual slice (skip own)
    const int c   = (wdx >> 3) & 127;
    const int p   = wdx & 7;
    roff[j]  = (sl * 128 + c) * 8 + p;
    obyte[j] = roff[j] * 8;
  }

  // ---- init own LDS slice to h_0 = 0; init probe vote
  if (tid == 0) g_ok = 1;
  {
    const int row = tid >> 4, ch = tid & 15;          // 16 rows x 16 chunks
    f16x8 z = {0, 0, 0, 0, 0, 0, 0, 0};
    *(f16x8*)(&hbuf[row][c0 + ch * 8]) = z;
  }
  __syncthreads();   // own slice + g_ok ready

  bool fastmode = true;
  const int xrow = tid >> 5;
  const int xcol = (tid & 31) * 8;

  for (int t = 0; t < T_; ++t) {
    const unsigned ut = (unsigned)t;
    const size_t slot_c = (size_t)((t & 1) ? NG : 0) + g;       // consume
    const size_t slot_p = (size_t)(((t + 1) & 1) ? NG : 0) + g; // publish

    // ---- (1) x_t loads (issued early, consumed at (3))
    const float* src = x + ((size_t)t * B_ + r0) * I_;
    const float4 xv0 = *(const float4*)(src + (size_t)xrow * I_ + xcol);
    const float4 xv1 = *(const float4*)(src + (size_t)xrow * I_ + xcol + 4);
    const float4 xv2 = *(const float4*)(src + (size_t)(xrow + 8) * I_ + xcol);
    const float4 xv3 = *(const float4*)(src + (size_t)(xrow + 8) * I_ + xcol + 4);

    // ---- (2) hs[t-1] = h_t own slice (fire-and-forget; ack drains in M1)
    if (t > 0) {
      const int row = tid >> 4, ch = tid & 15;
      *(uint4*)(hs + ((size_t)(t - 1) * B_ + r0 + row) * H_ + c0 + ch * 8) =
          *(const uint4*)(&hbuf[row][c0 + ch * 8]);
    }

    // ---- (3) M1: own-column K-range of h_t @ W_hh (no remote dep)
    f32x4 a0a = {0.f,0.f,0.f,0.f}, a0b = {0.f,0.f,0.f,0.f};
    f32x4 a1a = {0.f,0.f,0.f,0.f}, a1b = {0.f,0.f,0.f,0.f};
    #pragma unroll
    for (int kt = 0; kt < 4; ++kt) {
      const int pk = (s * 4 + kt) & 15;
      const f16x8 a = *(const f16x8*)(&hbuf[lrow][pk * 32 + kq]);
      a0b = __builtin_amdgcn_mfma_f32_16x16x32_f16(a, whh0[kt], a0b, 0, 0, 0);
      a1b = __builtin_amdgcn_mfma_f32_16x16x32_f16(a, whh1[kt], a1b, 0, 0, 0);
    }

    // ---- (4) x_t -> xbuf (forces x-load drain before the poll)
    *(f16x8*)(&xbuf[xrow][xcol])     = cvt8(xv0, xv1);
    *(f16x8*)(&xbuf[xrow + 8][xcol]) = cvt8(xv2, xv3);

    // ---- (5) poll remote h_t
    unsigned long long v[12];
    unsigned miss = 0xfffu;
    if (fastmode) {
      const unsigned long long* fb = ringf + slot_c * RING_WPG;
      const int limit = (t <= 1) ? 256 : 0x7fffffff;
      int rounds = 0;
      do {
        // 12 L2-local loads (sc0: bypass L1, served by same-XCD L2),
        // single trailing vmcnt(0) INSIDE the asm (no hoist hazard).
        asm volatile(
            "global_load_dwordx2 %0, %13, %12 sc0\n\t"
            "global_load_dwordx2 %1, %14, %12 sc0\n\t"
            "global_load_dwordx2 %2, %15, %12 sc0\n\t"
            "global_load_dwordx2 %3, %16, %12 sc0\n\t"
            "global_load_dwordx2 %4, %17, %12 sc0\n\t"
            "global_load_dwordx2 %5, %18, %12 sc0\n\t"
            "global_load_dwordx2 %6, %19, %12 sc0\n\t"
            "global_load_dwordx2 %7, %20, %12 sc0\n\t"
            "global_load_dwordx2 %8, %21, %12 sc0\n\t"
            "global_load_dwordx2 %9, %22, %12 sc0\n\t"
            "global_load_dwordx2 %10, %23, %12 sc0\n\t"
            "global_load_dwordx2 %11, %24, %12 sc0\n\t"
            "s_waitcnt vmcnt(0)"
            : "=&v"(v[0]), "=&v"(v[1]), "=&v"(v[2]), "=&v"(v[3]),
              "=&v"(v[4]), "=&v"(v[5]), "=&v"(v[6]), "=&v"(v[7]),
              "=&v"(v[8]), "=&v"(v[9]), "=&v"(v[10]), "=&v"(v[11])
            : "s"(fb), "v"(obyte[0]), "v"(obyte[1]), "v"(obyte[2]),
              "v"(obyte[3]), "v"(obyte[4]), "v"(obyte[5]), "v"(obyte[6]),
              "v"(obyte[7]), "v"(obyte[8]), "v"(obyte[9]), "v"(obyte[10]),
              "v"(obyte[11])
            : "memory");
        miss = 0u;
        #pragma unroll
        for (int j = 0; j < 12; ++j)
          if ((unsigned)(v[j] >> 32) != ut) miss |= 1u << j;
      } while (miss && ++rounds < limit);
      if (miss) g_ok = 0;   // probe failed -> block votes slow
    }
    if (miss) {
      // coherent fallback (agent atomics) for the words still pending
      const unsigned long long* rg = ring + slot_c * RING_WPG;
      while (miss) {
        #pragma unroll
        for (int j = 0; j < 12; ++j) {
          if (miss & (1u << j)) {
            const unsigned long long wv = __hip_atomic_load(
                &rg[roff[j]], __ATOMIC_RELAXED, __HIP_MEMORY_SCOPE_AGENT);
            if ((unsigned)(wv >> 32) == ut) { v[j] = wv; miss &= ~(1u << j); }
          }
        }
      }
    }
    // ---- (6) stage remote h_t -> hbuf
    #pragma unroll
    for (int j = 0; j < 12; ++j) {
      const int col = roff[j] >> 3;
      const int pr  = (roff[j] & 7) * 2;
      const unsigned lo = (unsigned)v[j];
      hbuf[pr + 0][col] =
          __builtin_bit_cast(_Float16, (unsigned short)(lo & 0xffff));
      hbuf[pr + 1][col] =
          __builtin_bit_cast(_Float16, (unsigned short)(lo >> 16));
    }
    __syncthreads();   // B2: remote h_t + x_t staged; M1 reads done
    if (t == 1) fastmode = (g_ok != 0);   // uniform commit (see header note)

    // ---- (7) M2: remote K-range of h_t @ W_hh + x_t @ W_ih
    #pragma unroll
    for (int kt = 4; kt < 16; ++kt) {
      const int pk = (s * 4 + kt) & 15;
      const f16x8 a = *(const f16x8*)(&hbuf[lrow][pk * 32 + kq]);
      if (kt < 10) {
        a0a = __builtin_amdgcn_mfma_f32_16x16x32_f16(a, whh0[kt], a0a, 0, 0, 0);
        a1a = __builtin_amdgcn_mfma_f32_16x16x32_f16(a, whh1[kt], a1a, 0, 0, 0);
      } else {
        a0b = __builtin_amdgcn_mfma_f32_16x16x32_f16(a, whh0[kt], a0b, 0, 0, 0);
        a1b = __builtin_amdgcn_mfma_f32_16x16x32_f16(a, whh1[kt], a1b, 0, 0, 0);
      }
    }
    #pragma unroll
    for (int kt = 0; kt < 8; ++kt) {
      const f16x8 a = *(const f16x8*)(&xbuf[lrow][kt * 32 + kq]);
      if (kt < 4) {
        a0a = __builtin_amdgcn_mfma_f32_16x16x32_f16(a, wih0[kt], a0a, 0, 0, 0);
        a1a = __builtin_amdgcn_mfma_f32_16x16x32_f16(a, wih1[kt], a1a, 0, 0, 0);
      } else {
        a0b = __builtin_amdgcn_mfma_f32_16x16x32_f16(a, wih0[kt], a0b, 0, 0, 0);
        a1b = __builtin_amdgcn_mfma_f32_16x16x32_f16(a, wih1[kt], a1b, 0, 0, 0);
      }
    }
    const f32x4 acc0 = a0a + a0b;
    const f32x4 acc1 = a1a + a1b;

    // ---- (8) tanh; publish h_{t+1}
    _Float16 e0[4], e1[4];
    #pragma unroll
    for (int r = 0; r < 4; ++r) {
      e0[r] = (_Float16)tanh_fast(acc0[r] + bias0);
      e1[r] = (_Float16)tanh_fast(acc1[r] + bias1);
    }
    const unsigned tag = (unsigned)(t + 1);
    if (fastmode) {     // fast ring: plain stores -> same-XCD L2
      unsigned long long* fn = ringf + slot_p * RING_WPG;
      fn[n0c * 8 + quad * 2 + 0] = pack2h(e0[0], e0[1], tag);
      fn[n0c * 8 + quad * 2 + 1] = pack2h(e0[2], e0[3], tag);
      fn[n1c * 8 + quad * 2 + 0] = pack2h(e1[0], e1[1], tag);
      fn[n1c * 8 + quad * 2 + 1] = pack2h(e1[2], e1[3], tag);
    }
    if (t == 0 || !fastmode) {   // coherent ring (dual during probe window)
      unsigned long long* rn = ring + slot_p * RING_WPG;
      __hip_atomic_store(&rn[n0c * 8 + quad * 2 + 0], pack2h(e0[0], e0[1], tag),
                         __ATOMIC_RELAXED, __HIP_MEMORY_SCOPE_AGENT);
      __hip_atomic_store(&rn[n0c * 8 + quad * 2 + 1], pack2h(e0[2], e0[3], tag),
                         __ATOMIC_RELAXED, __HIP_MEMORY_SCOPE_AGENT);
      __hip_atomic_store(&rn[n1c * 8 + quad * 2 + 0], pack2h(e1[0], e1[1], tag),
                         __ATOMIC_RELAXED, __HIP_MEMORY_SCOPE_AGENT);
      __hip_atomic_store(&rn[n1c * 8 + quad * 2 + 1], pack2h(e1[2], e1[3], tag),
                         __ATOMIC_RELAXED, __HIP_MEMORY_SCOPE_AGENT);
    }
    #pragma unroll
    for (int r = 0; r < 4; ++r) {
      hbuf[quad * 4 + r][n0c] = e0[r];
      hbuf[quad * 4 + r][n1c] = e1[r];
    }
    __syncthreads();   // B1: h_{t+1} own slice visible for next M1 / hs write
  }

  // ---- final: hs[T-1] = h_T own slice
  {
    const int row = tid >> 4, ch = tid & 15;
    *(uint4*)(hs + ((size_t)(T_ - 1) * B_ + r0 + row) * H_ + c0 + ch * 8) =
        *(const uint4*)(&hbuf[row][c0 + ch * 8]);
  }
}

// -------------------------------------------------------------------------
// Output head: out[m,o] = hs[m,:] @ w_fc[o,:] + b_fc[o]
// M=T*B=131072, N=256, K=512. 64x64 block tile, 4 waves in 2x2.
// n-dimension fastest so the 4 blocks sharing an A-tile are consecutive.
// -------------------------------------------------------------------------
__global__ __launch_bounds__(256) void fc_head(
    const _Float16* __restrict__ hs,  // [T*B, H]
    const float* __restrict__ w_fc,   // [I, H]
    const float* __restrict__ b_fc,   // [I]
    float* __restrict__ out)          // [T*B, I]
{
  const int tid  = threadIdx.x;
  const int lane = tid & 63;
  const int w    = tid >> 6;
  const int wm   = w & 1;
  const int wn   = w >> 1;
  const int m0   = blockIdx.y * 64;
  const int n0   = blockIdx.x * 64;
  const int lrow = lane & 15;
  const int quad = lane >> 4;
  const int kq   = quad * 8;

  __shared__ _Float16 As[64][32 + 8];
  __shared__ _Float16 Bs[64][32 + 8];

  f32x4 acc00 = {0.f,0.f,0.f,0.f}, acc01 = {0.f,0.f,0.f,0.f};
  f32x4 acc10 = {0.f,0.f,0.f,0.f}, acc11 = {0.f,0.f,0.f,0.f};

  const int srow = tid >> 2;
  const int skc  = (tid & 3) * 8;

  for (int k0 = 0; k0 < H_; k0 += 32) {
    *(uint4*)(&As[srow][skc]) =
        *(const uint4*)(hs + (size_t)(m0 + srow) * H_ + k0 + skc);
    *(f16x8*)(&Bs[srow][skc]) =
        cvt8(*(const float4*)(w_fc + (size_t)(n0 + srow) * H_ + k0 + skc),
             *(const float4*)(w_fc + (size_t)(n0 + srow) * H_ + k0 + skc + 4));
    __syncthreads();

    const f16x8 a0 = *(const f16x8*)(&As[wm * 32 + lrow][kq]);
    const f16x8 a1 = *(const f16x8*)(&As[wm * 32 + 16 + lrow][kq]);
    const f16x8 b0 = *(const f16x8*)(&Bs[wn * 32 + lrow][kq]);
    const f16x8 b1 = *(const f16x8*)(&Bs[wn * 32 + 16 + lrow][kq]);
    acc00 = __builtin_amdgcn_mfma_f32_16x16x32_f16(a0, b0, acc00, 0, 0, 0);
    acc01 = __builtin_amdgcn_mfma_f32_16x16x32_f16(a0, b1, acc01, 0, 0, 0);
    acc10 = __builtin_amdgcn_mfma_f32_16x16x32_f16(a1, b0, acc10, 0, 0, 0);
    acc11 = __builtin_amdgcn_mfma_f32_16x16x32_f16(a1, b1, acc11, 0, 0, 0);
    __syncthreads();
  }

  #pragma unroll
  for (int ni = 0; ni < 2; ++ni) {
    const int col = n0 + wn * 32 + ni * 16 + lrow;
    const float bf = b_fc[col];
    #pragma unroll
    for (int mi = 0; mi < 2; ++mi) {
      const f32x4 a = (mi == 0) ? (ni == 0 ? acc00 : acc01)
                                : (ni == 0 ? acc10 : acc11);
      #pragma unroll
      for (int r = 0; r < 4; ++r) {
        const int rowm = m0 + wm * 32 + mi * 16 + quad * 4 + r;
        out[(size_t)rowm * I_ + col] = a[r] + bf;
      }
    }
  }
}

extern "C" void kernel_launch(void* const* d_in, const int* in_sizes, int n_in,
                              void* d_out, int out_size, void* d_ws, size_t ws_size,
                              hipStream_t stream) {
  const float* x    = (const float*)d_in[0];
  const float* w_ih = (const float*)d_in[1];
  const float* w_hh = (const float*)d_in[2];
  const float* b_ih = (const float*)d_in[3];
  const float* b_hh = (const float*)d_in[4];
  const float* w_fc = (const float*)d_in[5];
  const float* b_fc = (const float*)d_in[6];
  float* out = (float*)d_out;

  unsigned long long* ring  = (unsigned long long*)d_ws;
  unsigned long long* ringf = (unsigned long long*)((char*)d_ws + RING_BYTES);
  _Float16* hs = (_Float16*)((char*)d_ws + 2 * RING_BYTES);

  // zero BOTH rings, both slots: slot0 -> (tag 0 = valid h0 = 0); slot1 ->
  // tag 0 never matches an odd step. Removes any stale-tag replay hazard.
  hipMemsetAsync(d_ws, 0, 2 * RING_BYTES, stream);

  rnn_recurrence<<<64, 256, 0, stream>>>(x, w_ih, w_hh, b_ih, b_hh, ring, ringf, hs);
  fc_head<<<dim3(4, 2048), 256, 0, stream>>>(hs, w_fc, b_fc, out);
}